// Round 5
// baseline (126.690 us; speedup 1.0000x reference)
//
#include <hip/hip_runtime.h>

#define NB    256
#define UNITS 1024
#define EDIM  1024
#define MEM   128
#define LDA   2048   // inputs row stride (EDIM + UNITS)

// d_out layout (floats): output[256*1024] | new_M_key[256*128*1024] | new_M_value[256*128*1024]
#define KEY_OFF ((size_t)NB * UNITS)
#define VAL_OFF (KEY_OFF + (size_t)NB * MEM * UNITS)

#define NGEMM 128                 // GEMM blocks (first in grid)
#define GROUP_F 4224              // GEMM: floats per split-K group region (As 32x68 + Bs 32x64)
#define SMEM_FLOATS 17424         // fused: h 1024 + o_s 16*1024 + z_s 16  (>= 4*GROUP_F)

typedef float nfloat4 __attribute__((ext_vector_type(4)));

__device__ __forceinline__ void nt_store4(float* p, float4 v) {
    nfloat4 nv = {v.x, v.y, v.z, v.w};
    __builtin_nontemporal_store(nv, (nfloat4*)p);
}

// Blocks 0..127: the two 256x1024x1024 fp32 GEMMs (row 127 of new_M_*), LDS-staged,
//   in-block split-K=4 (R4 structure, proven).
// Blocks 128..383: fused attention + shift, ONLINE softmax — single streaming pass:
//   read K-row & V-row together, write both shifted copies (nontemporal), accumulate
//   o += exp(l-8)*v and Z += exp(l-8) per wave; one end-of-kernel LDS combine.
__global__ __launch_bounds__(1024, 8) void k_all(
    const float* __restrict__ inputs, const float* __restrict__ M_key,
    const float* __restrict__ M_value, const float* __restrict__ W_key,
    const float* __restrict__ W_value, float* __restrict__ out)
{
    __shared__ __align__(16) float smem[SMEM_FLOATS];
    const int tid = threadIdx.x;

    if (blockIdx.x >= NGEMM) {
        // ========================= fused path (online softmax) =========================
        float* h_s = smem;                    // 1024
        float* o_s = smem + 1024;             // 16 x 1024 per-wave partials
        float* z_s = smem + 1024 + 16 * 1024; // 16

        const int b    = blockIdx.x - NGEMM;
        const int wave = tid >> 6;
        const int lane = tid & 63;

        h_s[tid] = inputs[(size_t)b * LDA + EDIM + tid];
        __syncthreads();

        const float4 h0 = *(const float4*)(&h_s[lane * 4]);
        const float4 h1 = *(const float4*)(&h_s[lane * 4 + 256]);
        const float4 h2 = *(const float4*)(&h_s[lane * 4 + 512]);
        const float4 h3 = *(const float4*)(&h_s[lane * 4 + 768]);

        const size_t mb = (size_t)b * (MEM * UNITS);
        const float* kb = M_key   + mb + lane * 4;
        const float* vb = M_value + mb + lane * 4;
        float*       ko = out + KEY_OFF + mb + lane * 4;
        float*       vo = out + VAL_OFF + mb + lane * 4;

        float4 o0 = {0.f,0.f,0.f,0.f}, o1 = o0, o2 = o0, o3 = o0;
        float  Zp = 0.f;

        #pragma unroll 2
        for (int r = 0; r < 8; ++r) {
            const int m = wave * 8 + r;
            const float* kr = kb + (size_t)m * UNITS;
            const float* vr = vb + (size_t)m * UNITS;
            float* kd = ko + (size_t)(m - 1) * UNITS;
            float* vd = vo + (size_t)(m - 1) * UNITS;

            // K chunks: load -> dot partial -> shifted store -> dead (low reg pressure)
            float acc;
            {
                float4 k = *(const float4*)(kr);
                acc = k.x*h0.x + k.y*h0.y + k.z*h0.z + k.w*h0.w;
                if (m > 0) nt_store4(kd, k);
                k = *(const float4*)(kr + 256);
                acc += k.x*h1.x + k.y*h1.y + k.z*h1.z + k.w*h1.w;
                if (m > 0) nt_store4(kd + 256, k);
                k = *(const float4*)(kr + 512);
                acc += k.x*h2.x + k.y*h2.y + k.z*h2.z + k.w*h2.w;
                if (m > 0) nt_store4(kd + 512, k);
                k = *(const float4*)(kr + 768);
                acc += k.x*h3.x + k.y*h3.y + k.z*h3.z + k.w*h3.w;
                if (m > 0) nt_store4(kd + 768, k);
            }
            #pragma unroll
            for (int off = 32; off > 0; off >>= 1)
                acc += __shfl_xor(acc, off);

            const float p = __expf(acc - 8.0f);   // softmax shift-invariant; |logit| << 90
            Zp += p;

            // V chunks: load -> shifted store -> weighted accumulate -> dead
            {
                float4 v = *(const float4*)(vr);
                if (m > 0) nt_store4(vd, v);
                o0.x = fmaf(p, v.x, o0.x); o0.y = fmaf(p, v.y, o0.y);
                o0.z = fmaf(p, v.z, o0.z); o0.w = fmaf(p, v.w, o0.w);
                v = *(const float4*)(vr + 256);
                if (m > 0) nt_store4(vd + 256, v);
                o1.x = fmaf(p, v.x, o1.x); o1.y = fmaf(p, v.y, o1.y);
                o1.z = fmaf(p, v.z, o1.z); o1.w = fmaf(p, v.w, o1.w);
                v = *(const float4*)(vr + 512);
                if (m > 0) nt_store4(vd + 512, v);
                o2.x = fmaf(p, v.x, o2.x); o2.y = fmaf(p, v.y, o2.y);
                o2.z = fmaf(p, v.z, o2.z); o2.w = fmaf(p, v.w, o2.w);
                v = *(const float4*)(vr + 768);
                if (m > 0) nt_store4(vd + 768, v);
                o3.x = fmaf(p, v.x, o3.x); o3.y = fmaf(p, v.y, o3.y);
                o3.z = fmaf(p, v.z, o3.z); o3.w = fmaf(p, v.w, o3.w);
            }
        }

        // per-wave partials -> LDS, one barrier, combine
        *(float4*)(&o_s[wave * 1024 + lane * 4])       = o0;
        *(float4*)(&o_s[wave * 1024 + lane * 4 + 256]) = o1;
        *(float4*)(&o_s[wave * 1024 + lane * 4 + 512]) = o2;
        *(float4*)(&o_s[wave * 1024 + lane * 4 + 768]) = o3;
        if (lane == 0) z_s[wave] = Zp;
        __syncthreads();

        float zt = 0.f;
        #pragma unroll
        for (int w = 0; w < 16; ++w) zt += z_s[w];
        float sv = 0.f;
        #pragma unroll
        for (int w = 0; w < 16; ++w) sv += o_s[w * 1024 + tid];
        out[(size_t)b * UNITS + tid] = sv / zt;
    } else {
        // ========================= GEMM path (R4 structure) =========================
        const int t  = blockIdx.x;            // 0..127
        const int w  = t >> 6;                // which W matrix
        const int r  = t & 63;
        const int mt = r >> 4;                // 0..3  (64 rows)
        const int nt = r & 15;                // 0..15 (64 cols)
        const int kc   = tid >> 8;            // 0..3 (split-K group)
        const int gtid = tid & 255;
        const int ty = gtid >> 4, tx = gtid & 15;

        float* region = smem + kc * GROUP_F;
        float (*As)[68] = (float (*)[68])region;            // [k][m]
        float (*Bs)[64] = (float (*)[64])(region + 2176);   // [k][n]
        const float* Wm = w ? W_value : W_key;

        float acc[4][4] = {};
        const int k0 = kc * 256;

        for (int kt = k0; kt < k0 + 256; kt += 32) {
            #pragma unroll
            for (int q = 0; q < 2; ++q) {
                const int f  = gtid * 2 + q;          // 0..511
                const int ar = f >> 3;                // 0..63
                const int ac = (f & 7) << 2;          // 0..28
                float4 a = *(const float4*)(inputs + (size_t)(mt * 64 + ar) * LDA + kt + ac);
                As[ac + 0][ar] = a.x;
                As[ac + 1][ar] = a.y;
                As[ac + 2][ar] = a.z;
                As[ac + 3][ar] = a.w;
            }
            #pragma unroll
            for (int q = 0; q < 2; ++q) {
                const int f  = gtid * 2 + q;
                const int br = f >> 4;                // 0..31
                const int bc = (f & 15) << 2;         // 0..60
                *(float4*)(&Bs[br][bc]) =
                    *(const float4*)(Wm + (size_t)(kt + br) * UNITS + nt * 64 + bc);
            }
            __syncthreads();

            #pragma unroll
            for (int kk = 0; kk < 32; ++kk) {
                const float4 av = *(const float4*)(&As[kk][ty * 4]);
                const float4 bv = *(const float4*)(&Bs[kk][tx * 4]);
                acc[0][0] += av.x * bv.x; acc[0][1] += av.x * bv.y; acc[0][2] += av.x * bv.z; acc[0][3] += av.x * bv.w;
                acc[1][0] += av.y * bv.x; acc[1][1] += av.y * bv.y; acc[1][2] += av.y * bv.z; acc[1][3] += av.y * bv.w;
                acc[2][0] += av.z * bv.x; acc[2][1] += av.z * bv.y; acc[2][2] += av.z * bv.z; acc[2][3] += av.z * bv.w;
                acc[3][0] += av.w * bv.x; acc[3][1] += av.w * bv.y; acc[3][2] += av.w * bv.z; acc[3][3] += av.w * bv.w;
            }
            __syncthreads();
        }

        // each group writes its 64x64 partial over its own As/Bs region
        #pragma unroll
        for (int i = 0; i < 4; ++i) {
            float4 v = {acc[i][0], acc[i][1], acc[i][2], acc[i][3]};
            *(float4*)(region + (ty * 4 + i) * 64 + tx * 4) = v;
        }
        __syncthreads();

        // block-wide reduce of the 4 partials -> row 127 of new_M_{key,value}
        {
            const int e   = tid * 4;                  // 0..4092
            const int row = e >> 6;                   // 0..63
            const int col = e & 63;
            float4 p0 = *(const float4*)(smem + 0 * GROUP_F + e);
            float4 p1 = *(const float4*)(smem + 1 * GROUP_F + e);
            float4 p2 = *(const float4*)(smem + 2 * GROUP_F + e);
            float4 p3 = *(const float4*)(smem + 3 * GROUP_F + e);
            float4 s = {p0.x + p1.x + p2.x + p3.x,
                        p0.y + p1.y + p2.y + p3.y,
                        p0.z + p1.z + p2.z + p3.z,
                        p0.w + p1.w + p2.w + p3.w};
            *(float4*)(out + (w ? VAL_OFF : KEY_OFF)
                       + (size_t)(mt * 64 + row) * (MEM * UNITS)
                       + (size_t)(MEM - 1) * UNITS + nt * 64 + col) = s;
        }
    }
}

extern "C" void kernel_launch(void* const* d_in, const int* in_sizes, int n_in,
                              void* d_out, int out_size, void* d_ws, size_t ws_size,
                              hipStream_t stream)
{
    const float* inputs  = (const float*)d_in[0];
    const float* M_key   = (const float*)d_in[1];
    const float* M_value = (const float*)d_in[2];
    const float* W_key   = (const float*)d_in[3];
    const float* W_value = (const float*)d_in[4];
    float* out = (float*)d_out;

    hipLaunchKernelGGL(k_all, dim3(NGEMM + NB), dim3(1024), 0, stream,
                       inputs, M_key, M_value, W_key, W_value, out);
}